// Round 8
// baseline (107.113 us; speedup 1.0000x reference)
//
#include <hip/hip_runtime.h>

// HardNMS fused kernel — LDS-free, wave-private register sliding window.
// Round 8: R4 structure EXACTLY (depth-2 prefetch RWa/RWb, shfl halo,
// period-4 row rotation), but SH=16->8 and grid 1024->2048 blocks with
// __launch_bounds__(256,8): 8 blocks/CU => 8 waves/SIMD (R4 was grid-capped
// at 4). Single-variable experiment vs R4: wave-level TLP.
// x: [B=16, 2, H=1024, W=1024] f32 -> out: [16, 1, 1024, 1024] f32
// xp   = relu(x[:,1] - x[:,0] - 0.1)
// xNMS = 256 * prod_{8 nbrs} relu(xp - xp_nb)   (zero-padded)
// out  = xp * maxpool3x3(xNMS)                  (xNMS >= 0 so zero-pad == -inf pad)

constexpr int Wd = 1024, Hd = 1024, Bd = 16;
constexpr int SH = 8;                  // output rows per wave strip
constexpr float EPS = 0.1f;

__device__ __forceinline__ float max3(float a, float b, float c) {
    return fmaxf(fmaxf(a, b), c);
}
__device__ __forceinline__ float reluf(float v) { return fmaxf(v, 0.f); }

struct Raw { float4 a, c; float2 ea, ec; };

__global__ __launch_bounds__(256, 8) void hardnms_kernel(
    const float* __restrict__ xin, float* __restrict__ out) {
    const int tid   = threadIdx.x;
    const int lane  = tid & 63;
    const int wid   = tid >> 6;
    const int xbase = blockIdx.x * 256;
    const int col0  = xbase + lane * 4;
    const int y0    = (blockIdx.y * 4 + wid) * SH;
    const int b     = blockIdx.z;
    const float* __restrict__ p0 = xin + (size_t)(b * 2 + 0) * Hd * Wd;
    const float* __restrict__ p1 = xin + (size_t)(b * 2 + 1) * Hd * Wd;
    const bool lOK = (xbase > 0);
    const bool rOK = (xbase + 256 < Wd);

    Raw RW0, RW1;
    RW0.ea = RW0.ec = RW1.ea = RW1.ec = make_float2(0.f, 0.f);

    // Issue global loads for row gy (2 rows ahead of use).
    #define ISSUE(gy, RW) do {                                              \
        const int gy_ = (gy);                                               \
        if ((unsigned)gy_ < (unsigned)Hd) {                                 \
            const size_t ro_ = (size_t)gy_ * Wd;                            \
            (RW).a = *(const float4*)(p0 + ro_ + col0);                     \
            (RW).c = *(const float4*)(p1 + ro_ + col0);                     \
            if (lane == 0) {                                                \
                if (lOK) {                                                  \
                    (RW).ea = *(const float2*)(p0 + ro_ + xbase - 2);       \
                    (RW).ec = *(const float2*)(p1 + ro_ + xbase - 2);       \
                }                                                           \
            } else if (lane == 63) {                                        \
                if (rOK) {                                                  \
                    (RW).ea = *(const float2*)(p0 + ro_ + xbase + 256);     \
                    (RW).ec = *(const float2*)(p1 + ro_ + xbase + 256);     \
                }                                                           \
            }                                                               \
        } else {                                                            \
            (RW).a = make_float4(0.f, 0.f, 0.f, 0.f);                       \
            (RW).c = make_float4(0.f, 0.f, 0.f, 0.f);                       \
            (RW).ea = (RW).ec = make_float2(0.f, 0.f);                      \
        }                                                                   \
    } while (0)

    // Build xp 8-span S[i] = xp at col0-2+i from raw row.
    #define MAKEXP(RW, S) do {                                              \
        const float x0_ = reluf((RW).c.x - (RW).a.x - EPS);                 \
        const float x1_ = reluf((RW).c.y - (RW).a.y - EPS);                 \
        const float x2_ = reluf((RW).c.z - (RW).a.z - EPS);                 \
        const float x3_ = reluf((RW).c.w - (RW).a.w - EPS);                 \
        S[2] = x0_; S[3] = x1_; S[4] = x2_; S[5] = x3_;                     \
        S[0] = __shfl_up(x2_, 1);  S[1] = __shfl_up(x3_, 1);                \
        S[6] = __shfl_down(x0_, 1); S[7] = __shfl_down(x1_, 1);             \
        const float e0_ = reluf((RW).ec.x - (RW).ea.x - EPS);               \
        const float e1_ = reluf((RW).ec.y - (RW).ea.y - EPS);               \
        if (lane == 0)  { S[0] = lOK ? e0_ : 0.f; S[1] = lOK ? e1_ : 0.f; } \
        if (lane == 63) { S[6] = rOK ? e0_ : 0.f; S[7] = rOK ? e1_ : 0.f; } \
    } while (0)

    // xNMS row (6 wide, cols col0-1..col0+4) + 3-wide rowmax -> rm[4]
    #define ROWMAX_NM(A, B, C, rm) do {                                     \
        float nm_[6];                                                       \
        _Pragma("unroll")                                                   \
        for (int j = 0; j < 6; ++j) {                                       \
            const float c_ = B[j + 1];                                      \
            float p_;                                                       \
            p_  = reluf(c_ - A[j    ]);                                     \
            p_ *= reluf(c_ - A[j + 1]);                                     \
            p_ *= reluf(c_ - A[j + 2]);                                     \
            p_ *= reluf(c_ - B[j    ]);                                     \
            p_ *= reluf(c_ - B[j + 2]);                                     \
            p_ *= reluf(c_ - C[j    ]);                                     \
            p_ *= reluf(c_ - C[j + 1]);                                     \
            p_ *= reluf(c_ - C[j + 2]);                                     \
            nm_[j] = p_;                                                    \
        }                                                                   \
        rm[0] = max3(nm_[0], nm_[1], nm_[2]);                               \
        rm[1] = max3(nm_[1], nm_[2], nm_[3]);                               \
        rm[2] = max3(nm_[2], nm_[3], nm_[4]);                               \
        rm[3] = max3(nm_[3], nm_[4], nm_[5]);                               \
    } while (0)

    #define EMIT(CTR, ra, rb, rc) do {                                      \
        float4 o_;                                                          \
        o_.x = CTR[2] * 256.f * max3(ra[0], rb[0], rc[0]);                  \
        o_.y = CTR[3] * 256.f * max3(ra[1], rb[1], rc[1]);                  \
        o_.z = CTR[4] * 256.f * max3(ra[2], rb[2], rc[2]);                  \
        o_.w = CTR[5] * 256.f * max3(ra[3], rb[3], rc[3]);                  \
        *(float4*)po = o_;                                                  \
        po += Wd;                                                           \
    } while (0)

    float R0[8], R1[8], R2[8], R3[8];
    float rm0[4], rm1[4], rm2[4], rm3[4];

    // Prologue: rows y0-2 .. y0+1 in R2,R3,R0,R1 (row r lives in R[r&3]);
    // raw loads stay 2 rows ahead.
    ISSUE(y0 - 2, RW0);
    ISSUE(y0 - 1, RW1);
    MAKEXP(RW0, R2);                      // row y0-2
    ISSUE(y0 + 0, RW0);
    MAKEXP(RW1, R3);                      // row y0-1
    ISSUE(y0 + 1, RW1);
    MAKEXP(RW0, R0);                      // row y0
    ISSUE(y0 + 2, RW0);
    ROWMAX_NM(R2, R3, R0, rm3);           // nm row y0-1
    MAKEXP(RW1, R1);                      // row y0+1
    ISSUE(y0 + 3, RW1);
    ROWMAX_NM(R3, R0, R1, rm0);           // nm row y0

    float* po = out + (size_t)b * Hd * Wd + (size_t)y0 * Wd + col0;

    // Steady state: step k consumes raw row k+2, issues row k+4,
    // computes nm row k+1, emits output row k.  Period-4 register rotation.
    #pragma unroll
    for (int k4 = 0; k4 < SH / 4; ++k4) {
        const int kb = k4 * 4;
        // k = kb+0
        MAKEXP(RW0, R2);
        if (kb + 0 <= SH - 3) ISSUE(y0 + kb + 4, RW0);
        ROWMAX_NM(R0, R1, R2, rm1);
        EMIT(R0, rm3, rm0, rm1);
        // k = kb+1
        MAKEXP(RW1, R3);
        if (kb + 1 <= SH - 3) ISSUE(y0 + kb + 5, RW1);
        ROWMAX_NM(R1, R2, R3, rm2);
        EMIT(R1, rm0, rm1, rm2);
        // k = kb+2
        MAKEXP(RW0, R0);
        if (kb + 2 <= SH - 3) ISSUE(y0 + kb + 6, RW0);
        ROWMAX_NM(R2, R3, R0, rm3);
        EMIT(R2, rm1, rm2, rm3);
        // k = kb+3
        MAKEXP(RW1, R1);
        if (kb + 3 <= SH - 3) ISSUE(y0 + kb + 7, RW1);
        ROWMAX_NM(R3, R0, R1, rm0);
        EMIT(R3, rm2, rm3, rm0);
    }

    #undef ISSUE
    #undef MAKEXP
    #undef ROWMAX_NM
    #undef EMIT
}

extern "C" void kernel_launch(void* const* d_in, const int* in_sizes, int n_in,
                              void* d_out, int out_size, void* d_ws, size_t ws_size,
                              hipStream_t stream) {
    const float* xin = (const float*)d_in[0];
    float* out = (float*)d_out;
    dim3 grid(Wd / 256, Hd / (4 * SH), Bd);   // (4, 32, 16) = 2048 blocks
    hardnms_kernel<<<grid, dim3(256), 0, stream>>>(xin, out);
}

// Round 10
// 41.370 us; speedup vs baseline: 2.5891x; 2.5891x over previous
//
#include <hip/hip_runtime.h>

// HardNMS fused kernel — LDS-free, wave-private register sliding window.
// Round 9b: compile fix (nontemporal store needs a NATIVE vector type, not
// HIP_vector_type). Same experiment as R9: R4 structure (48.3us best) +
//   1. XCD-aware chunked block swizzle (1024 blocks = 8 XCDs x 128)
//   2. __builtin_nontemporal_store for output (via ext_vector_type alias)
// x: [B=16, 2, H=1024, W=1024] f32 -> out: [16, 1, 1024, 1024] f32
// xp   = relu(x[:,1] - x[:,0] - 0.1)
// xNMS = 256 * prod_{8 nbrs} relu(xp - xp_nb)   (zero-padded)
// out  = xp * maxpool3x3(xNMS)                  (xNMS >= 0 so zero-pad == -inf pad)

constexpr int Wd = 1024, Hd = 1024, Bd = 16;
constexpr int SH = 16;                 // output rows per wave strip
constexpr float EPS = 0.1f;
constexpr int NBLK = (Wd / 256) * (Hd / (4 * SH)) * Bd;   // 4*16*16 = 1024
constexpr int NXCD = 8;

typedef float f32x4 __attribute__((ext_vector_type(4)));

__device__ __forceinline__ float max3(float a, float b, float c) {
    return fmaxf(fmaxf(a, b), c);
}
__device__ __forceinline__ float reluf(float v) { return fmaxf(v, 0.f); }

struct Raw { float4 a, c; float2 ea, ec; };

__global__ __launch_bounds__(256, 4) void hardnms_kernel(
    const float* __restrict__ xin, float* __restrict__ out) {
    const int tid   = threadIdx.x;
    const int lane  = tid & 63;
    const int wid   = tid >> 6;

    // XCD-aware chunked swizzle (bijective: NBLK % NXCD == 0).
    const int bid  = blockIdx.x;
    const int swz  = (bid % NXCD) * (NBLK / NXCD) + bid / NXCD;
    // Decode work coords (x fastest, then y-tile, then batch).
    const int xt   = swz & 3;             // 0..3
    const int yt   = (swz >> 2) & 15;     // 0..15
    const int b    = swz >> 6;            // 0..15

    const int xbase = xt * 256;
    const int col0  = xbase + lane * 4;
    const int y0    = (yt * 4 + wid) * SH;
    const float* __restrict__ p0 = xin + (size_t)(b * 2 + 0) * Hd * Wd;
    const float* __restrict__ p1 = xin + (size_t)(b * 2 + 1) * Hd * Wd;
    const bool lOK = (xbase > 0);
    const bool rOK = (xbase + 256 < Wd);

    Raw RW0, RW1;
    RW0.ea = RW0.ec = RW1.ea = RW1.ec = make_float2(0.f, 0.f);

    // Issue global loads for row gy (2 rows ahead of use).
    #define ISSUE(gy, RW) do {                                              \
        const int gy_ = (gy);                                               \
        if ((unsigned)gy_ < (unsigned)Hd) {                                 \
            const size_t ro_ = (size_t)gy_ * Wd;                            \
            (RW).a = *(const float4*)(p0 + ro_ + col0);                     \
            (RW).c = *(const float4*)(p1 + ro_ + col0);                     \
            if (lane == 0) {                                                \
                if (lOK) {                                                  \
                    (RW).ea = *(const float2*)(p0 + ro_ + xbase - 2);       \
                    (RW).ec = *(const float2*)(p1 + ro_ + xbase - 2);       \
                }                                                           \
            } else if (lane == 63) {                                        \
                if (rOK) {                                                  \
                    (RW).ea = *(const float2*)(p0 + ro_ + xbase + 256);     \
                    (RW).ec = *(const float2*)(p1 + ro_ + xbase + 256);     \
                }                                                           \
            }                                                               \
        } else {                                                            \
            (RW).a = make_float4(0.f, 0.f, 0.f, 0.f);                       \
            (RW).c = make_float4(0.f, 0.f, 0.f, 0.f);                       \
            (RW).ea = (RW).ec = make_float2(0.f, 0.f);                      \
        }                                                                   \
    } while (0)

    // Build xp 8-span S[i] = xp at col0-2+i from raw row.
    #define MAKEXP(RW, S) do {                                              \
        const float x0_ = reluf((RW).c.x - (RW).a.x - EPS);                 \
        const float x1_ = reluf((RW).c.y - (RW).a.y - EPS);                 \
        const float x2_ = reluf((RW).c.z - (RW).a.z - EPS);                 \
        const float x3_ = reluf((RW).c.w - (RW).a.w - EPS);                 \
        S[2] = x0_; S[3] = x1_; S[4] = x2_; S[5] = x3_;                     \
        S[0] = __shfl_up(x2_, 1);  S[1] = __shfl_up(x3_, 1);                \
        S[6] = __shfl_down(x0_, 1); S[7] = __shfl_down(x1_, 1);             \
        const float e0_ = reluf((RW).ec.x - (RW).ea.x - EPS);               \
        const float e1_ = reluf((RW).ec.y - (RW).ea.y - EPS);               \
        if (lane == 0)  { S[0] = lOK ? e0_ : 0.f; S[1] = lOK ? e1_ : 0.f; } \
        if (lane == 63) { S[6] = rOK ? e0_ : 0.f; S[7] = rOK ? e1_ : 0.f; } \
    } while (0)

    // xNMS row (6 wide, cols col0-1..col0+4) + 3-wide rowmax -> rm[4]
    #define ROWMAX_NM(A, B, C, rm) do {                                     \
        float nm_[6];                                                       \
        _Pragma("unroll")                                                   \
        for (int j = 0; j < 6; ++j) {                                       \
            const float c_ = B[j + 1];                                      \
            float p_;                                                       \
            p_  = reluf(c_ - A[j    ]);                                     \
            p_ *= reluf(c_ - A[j + 1]);                                     \
            p_ *= reluf(c_ - A[j + 2]);                                     \
            p_ *= reluf(c_ - B[j    ]);                                     \
            p_ *= reluf(c_ - B[j + 2]);                                     \
            p_ *= reluf(c_ - C[j    ]);                                     \
            p_ *= reluf(c_ - C[j + 1]);                                     \
            p_ *= reluf(c_ - C[j + 2]);                                     \
            nm_[j] = p_;                                                    \
        }                                                                   \
        rm[0] = max3(nm_[0], nm_[1], nm_[2]);                               \
        rm[1] = max3(nm_[1], nm_[2], nm_[3]);                               \
        rm[2] = max3(nm_[2], nm_[3], nm_[4]);                               \
        rm[3] = max3(nm_[3], nm_[4], nm_[5]);                               \
    } while (0)

    #define EMIT(CTR, ra, rb, rc) do {                                      \
        f32x4 o_;                                                           \
        o_.x = CTR[2] * 256.f * max3(ra[0], rb[0], rc[0]);                  \
        o_.y = CTR[3] * 256.f * max3(ra[1], rb[1], rc[1]);                  \
        o_.z = CTR[4] * 256.f * max3(ra[2], rb[2], rc[2]);                  \
        o_.w = CTR[5] * 256.f * max3(ra[3], rb[3], rc[3]);                  \
        __builtin_nontemporal_store(o_, (f32x4*)po);                        \
        po += Wd;                                                           \
    } while (0)

    float R0[8], R1[8], R2[8], R3[8];
    float rm0[4], rm1[4], rm2[4], rm3[4];

    // Prologue: rows y0-2 .. y0+1 in R2,R3,R0,R1 (row r lives in R[r&3]);
    // raw loads stay 2 rows ahead.
    ISSUE(y0 - 2, RW0);
    ISSUE(y0 - 1, RW1);
    MAKEXP(RW0, R2);                      // row y0-2
    ISSUE(y0 + 0, RW0);
    MAKEXP(RW1, R3);                      // row y0-1
    ISSUE(y0 + 1, RW1);
    MAKEXP(RW0, R0);                      // row y0
    ISSUE(y0 + 2, RW0);
    ROWMAX_NM(R2, R3, R0, rm3);           // nm row y0-1
    MAKEXP(RW1, R1);                      // row y0+1
    ISSUE(y0 + 3, RW1);
    ROWMAX_NM(R3, R0, R1, rm0);           // nm row y0

    float* po = out + (size_t)b * Hd * Wd + (size_t)y0 * Wd + col0;

    // Steady state: step k consumes raw row k+2, issues row k+4,
    // computes nm row k+1, emits output row k.  Period-4 register rotation.
    #pragma unroll
    for (int k4 = 0; k4 < SH / 4; ++k4) {
        const int kb = k4 * 4;
        // k = kb+0
        MAKEXP(RW0, R2);
        if (kb + 0 <= SH - 3) ISSUE(y0 + kb + 4, RW0);
        ROWMAX_NM(R0, R1, R2, rm1);
        EMIT(R0, rm3, rm0, rm1);
        // k = kb+1
        MAKEXP(RW1, R3);
        if (kb + 1 <= SH - 3) ISSUE(y0 + kb + 5, RW1);
        ROWMAX_NM(R1, R2, R3, rm2);
        EMIT(R1, rm0, rm1, rm2);
        // k = kb+2
        MAKEXP(RW0, R0);
        if (kb + 2 <= SH - 3) ISSUE(y0 + kb + 6, RW0);
        ROWMAX_NM(R2, R3, R0, rm3);
        EMIT(R2, rm1, rm2, rm3);
        // k = kb+3
        MAKEXP(RW1, R1);
        if (kb + 3 <= SH - 3) ISSUE(y0 + kb + 7, RW1);
        ROWMAX_NM(R3, R0, R1, rm0);
        EMIT(R3, rm2, rm3, rm0);
    }

    #undef ISSUE
    #undef MAKEXP
    #undef ROWMAX_NM
    #undef EMIT
}

extern "C" void kernel_launch(void* const* d_in, const int* in_sizes, int n_in,
                              void* d_out, int out_size, void* d_ws, size_t ws_size,
                              hipStream_t stream) {
    const float* xin = (const float*)d_in[0];
    float* out = (float*)d_out;
    hardnms_kernel<<<dim3(NBLK), dim3(256), 0, stream>>>(xin, out);
}